// Round 3
// baseline (84.299 us; speedup 1.0000x reference)
//
#include <hip/hip_runtime.h>
#include <math.h>

#define OBS 512
#define ATT 128

__device__ __forceinline__ void fma4(float4& a, float s, const float4& w) {
  a.x = fmaf(s, w.x, a.x);
  a.y = fmaf(s, w.y, a.y);
  a.z = fmaf(s, w.z, a.z);
  a.w = fmaf(s, w.w, a.w);
}

// K0: WphiT[k][dd] = Wphi[dd][k]  (128x512 fp32, 256 KB)
__global__ void transpose_wphi_k(const float* __restrict__ wphi,
                                 float* __restrict__ wphiT) {
  int idx = blockIdx.x * 256 + threadIdx.x;   // 0..65535
  int k  = idx >> 9;
  int dd = idx & 511;
  wphiT[idx] = wphi[dd * ATT + k];
}

// K1: per block 8 rows: Q = A.Wpsi (LDS), then U = Q.WphiT -> global U
__launch_bounds__(256, 2)
__global__ void proj_k(const float* __restrict__ A,      // (4096,512)
                       const float* __restrict__ Wpsi,   // (512,128)
                       const float* __restrict__ WphiT,  // (128,512)
                       float* __restrict__ U)            // (4096,512)
{
  __shared__ __align__(16) float As[8 * 512];   // 16 KB, rows flat
  __shared__ __align__(16) float Qs[8 * 128];   // 4 KB,  rows flat
  const int tid = threadIdx.x;
  const int g0  = blockIdx.x * 8;

  // stage 8 A-rows (coalesced float4 copy)
  {
    const float4* src = (const float4*)(A + (size_t)g0 * OBS);
    float4* dst = (float4*)As;
#pragma unroll
    for (int j = 0; j < 4; ++j) dst[tid + j * 256] = src[tid + j * 256];
  }
  __syncthreads();

  // phase 1: Q[r][k0..k0+4) ; thread = (kg = tid&31, rg = tid>>5 -> one row)
  {
    const int kg = tid & 31;
    const int rg = tid >> 5;
    float4 acc = make_float4(0.f, 0.f, 0.f, 0.f);
    const float4* wp4 = (const float4*)Wpsi;
    const float4* as4 = (const float4*)(As + rg * OBS);
#pragma unroll 4
    for (int dq = 0; dq < 128; ++dq) {
      float4 av = as4[dq];                       // LDS f4 broadcast (2 addrs/wave)
      float4 w0 = wp4[(dq * 4 + 0) * 32 + kg];   // Wpsi rows, coalesced
      float4 w1 = wp4[(dq * 4 + 1) * 32 + kg];
      float4 w2 = wp4[(dq * 4 + 2) * 32 + kg];
      float4 w3 = wp4[(dq * 4 + 3) * 32 + kg];
      fma4(acc, av.x, w0);
      fma4(acc, av.y, w1);
      fma4(acc, av.z, w2);
      fma4(acc, av.w, w3);
    }
    ((float4*)Qs)[rg * 32 + kg] = acc;
  }
  __syncthreads();

  // phase 2: U[r][dd] = sum_k Q[r][k]*WphiT[k][dd]
  // thread = (cg = tid&127 -> dd f4-group, rh = tid>>7 -> 4 rows)
  {
    const int cg = tid & 127;
    const int rh = tid >> 7;
    float4 acc[4];
#pragma unroll
    for (int i = 0; i < 4; ++i) acc[i] = make_float4(0.f, 0.f, 0.f, 0.f);
    const float4* wt4 = (const float4*)WphiT;
    const float4* qs4 = (const float4*)Qs;
#pragma unroll 2
    for (int kq = 0; kq < 32; ++kq) {
      float4 q0 = qs4[(rh * 4 + 0) * 32 + kq];   // uniform -> LDS broadcast
      float4 q1 = qs4[(rh * 4 + 1) * 32 + kq];
      float4 q2 = qs4[(rh * 4 + 2) * 32 + kq];
      float4 q3 = qs4[(rh * 4 + 3) * 32 + kq];
      float qa[4] = {q0.x, q0.y, q0.z, q0.w};
      float qb[4] = {q1.x, q1.y, q1.z, q1.w};
      float qc[4] = {q2.x, q2.y, q2.z, q2.w};
      float qd[4] = {q3.x, q3.y, q3.z, q3.w};
#pragma unroll
      for (int j = 0; j < 4; ++j) {
        float4 wt = wt4[(size_t)(kq * 4 + j) * 128 + cg];  // 1KB/wave coalesced
        fma4(acc[0], qa[j], wt);
        fma4(acc[1], qb[j], wt);
        fma4(acc[2], qc[j], wt);
        fma4(acc[3], qd[j], wt);
      }
    }
    float4* U4 = (float4*)U;
#pragma unroll
    for (int i = 0; i < 4; ++i)
      U4[(size_t)(g0 + rh * 4 + i) * 128 + cg] = acc[i];
  }
}

// K2: pure stream. wave = one (b,e) row: beta = u.v, softmax over 16 a.
// No LDS, no barriers.
__launch_bounds__(256)
__global__ void stream_k(const float* __restrict__ V,   // (4096,16,512)
                         const float* __restrict__ U,   // (4096,512)
                         float* __restrict__ Out)       // (4096,16)
{
  const int lane = threadIdx.x & 63;
  const int wave = threadIdx.x >> 6;
  const size_t g = (size_t)blockIdx.x * 4 + wave;

  const float4* vrow = (const float4*)V + g * 2048;  // 16 x 128 f4
  const float4* ur   = (const float4*)U + g * 128;
  const float4 uf0 = ur[lane * 2];
  const float4 uf1 = ur[lane * 2 + 1];

  float acc[16];
#pragma unroll
  for (int ag = 0; ag < 2; ++ag) {
    float4 va[16];
#pragma unroll
    for (int j = 0; j < 8; ++j) {
      va[j * 2]     = vrow[(size_t)(ag * 8 + j) * 128 + lane * 2];
      va[j * 2 + 1] = vrow[(size_t)(ag * 8 + j) * 128 + lane * 2 + 1];
    }
#pragma unroll
    for (int j = 0; j < 8; ++j) {
      float s;
      s = uf0.x * va[j * 2].x;
      s = fmaf(uf0.y, va[j * 2].y, s);
      s = fmaf(uf0.z, va[j * 2].z, s);
      s = fmaf(uf0.w, va[j * 2].w, s);
      s = fmaf(uf1.x, va[j * 2 + 1].x, s);
      s = fmaf(uf1.y, va[j * 2 + 1].y, s);
      s = fmaf(uf1.z, va[j * 2 + 1].z, s);
      s = fmaf(uf1.w, va[j * 2 + 1].w, s);
      acc[ag * 8 + j] = s;
    }
  }

#pragma unroll
  for (int a = 0; a < 16; ++a) {
    float v = acc[a];
    v += __shfl_xor(v, 32, 64);
    v += __shfl_xor(v, 16, 64);
    v += __shfl_xor(v,  8, 64);
    v += __shfl_xor(v,  4, 64);
    v += __shfl_xor(v,  2, 64);
    v += __shfl_xor(v,  1, 64);
    acc[a] = v;
  }

  float mx = acc[0];
#pragma unroll
  for (int a = 1; a < 16; ++a) mx = fmaxf(mx, acc[a]);
  float ssum = 0.f;
#pragma unroll
  for (int a = 0; a < 16; ++a) { acc[a] = __expf(acc[a] - mx); ssum += acc[a]; }
  const float inv = 1.0f / ssum;

  if (lane == 0) {
    float4* o4 = (float4*)(Out + g * 16);
    o4[0] = make_float4(acc[0]*inv,  acc[1]*inv,  acc[2]*inv,  acc[3]*inv);
    o4[1] = make_float4(acc[4]*inv,  acc[5]*inv,  acc[6]*inv,  acc[7]*inv);
    o4[2] = make_float4(acc[8]*inv,  acc[9]*inv,  acc[10]*inv, acc[11]*inv);
    o4[3] = make_float4(acc[12]*inv, acc[13]*inv, acc[14]*inv, acc[15]*inv);
  }
}

extern "C" void kernel_launch(void* const* d_in, const int* in_sizes, int n_in,
                              void* d_out, int out_size, void* d_ws, size_t ws_size,
                              hipStream_t stream) {
  (void)in_sizes; (void)n_in; (void)out_size; (void)ws_size;
  const float* A    = (const float*)d_in[0];  // agent_observation (128,32,512)
  const float* V    = (const float*)d_in[1];  // visible_observations (128,32,16,512)
  const float* Wpsi = (const float*)d_in[2];  // (512,128)
  const float* Wphi = (const float*)d_in[3];  // (512,128)
  float* Out   = (float*)d_out;               // (4096,16) fp32

  float* WphiT = (float*)d_ws;                // 256 KB
  float* U     = (float*)d_ws + 65536;        // 8 MB

  transpose_wphi_k<<<256, 256, 0, stream>>>(Wphi, WphiT);
  proj_k<<<512, 256, 0, stream>>>(A, Wpsi, WphiT, U);
  stream_k<<<1024, 256, 0, stream>>>(V, U, Out);
}

// Round 4
// 70.492 us; speedup vs baseline: 1.1959x; 1.1959x over previous
//
#include <hip/hip_runtime.h>
#include <math.h>

#define OBS 512
#define ATT 128
#define RPB 8   // (b,e) rows per block

#define AS1 __attribute__((address_space(1)))
#define AS3 __attribute__((address_space(3)))

#define WAITVM(n) asm volatile("s_waitcnt vmcnt(" #n ")" ::: "memory")

// K0: WphiT[k][dd] = Wphi[dd][k]  (128x512 fp32, 256 KB)
__global__ void transpose_wphi_k(const float* __restrict__ wphi,
                                 float* __restrict__ wphiT) {
  int idx = blockIdx.x * 256 + threadIdx.x;   // 0..65535
  int k  = idx >> 9;
  int dd = idx & 511;
  wphiT[idx] = wphi[dd * ATT + k];
}

__device__ __forceinline__ void fma4(float4& a, float s, const float4& w) {
  a.x = fmaf(s, w.x, a.x);
  a.y = fmaf(s, w.y, a.y);
  a.z = fmaf(s, w.z, a.z);
  a.w = fmaf(s, w.w, a.w);
}

__device__ __forceinline__ float wave_sum(float v) {
  v += __shfl_xor(v, 32, 64);
  v += __shfl_xor(v, 16, 64);
  v += __shfl_xor(v,  8, 64);
  v += __shfl_xor(v,  4, 64);
  v += __shfl_xor(v,  2, 64);
  v += __shfl_xor(v,  1, 64);
  return v;
}

// LDS float offsets (all scratch dies before the V-ring is written):
//   A-stage [0,4096) ; q [4096,5120) ; u [5120,9216) ; V-ring slots [0,16384)
// V-ring: slot s (s=a&3) at s*4096; wave w region +w*1024: row 2w [0,512),
// row 2w+1 [512,1024). Each wave loads/consumes only its own region.
__launch_bounds__(256, 2)
__global__ void entity_attn_k(const float* __restrict__ A,     // (4096,512)
                              const float* __restrict__ V,     // (4096,16,512)
                              const float* __restrict__ Wpsi,  // (512,128)
                              const float* __restrict__ WphiT, // (128,512) ws
                              float* __restrict__ Out)         // (4096,16)
{
  __shared__ __align__(16) float S[16384];   // 64 KB
  const int tid  = threadIdx.x;
  const int lane = tid & 63;
  const int w    = tid >> 6;                 // wave 0..3, owns rows 2w,2w+1
  const int g0   = blockIdx.x * RPB;

  // ---- stage A: 8 rows, coalesced flat copy (16 KB) ----
  {
    const float4* src = (const float4*)(A + (size_t)g0 * OBS);
    float4* dst = (float4*)S;
#pragma unroll
    for (int j = 0; j < 4; ++j) dst[tid + j * 256] = src[tid + j * 256];
  }
  __syncthreads();

  // ---- q[r][k] = sum_d A[r][d] Wpsi[d][k]; thread = (kg=tid&31, rg=tid>>5) ----
  {
    const int kg = tid & 31;
    const int rg = tid >> 5;
    float4 acc = make_float4(0.f, 0.f, 0.f, 0.f);
    const float4* wp4 = (const float4*)Wpsi;
    const float4* as4 = (const float4*)(S + rg * OBS);
#pragma unroll 4
    for (int dq = 0; dq < 128; ++dq) {
      float4 av = as4[dq];                     // LDS broadcast
      fma4(acc, av.x, wp4[(dq * 4 + 0) * 32 + kg]);
      fma4(acc, av.y, wp4[(dq * 4 + 1) * 32 + kg]);
      fma4(acc, av.z, wp4[(dq * 4 + 2) * 32 + kg]);
      fma4(acc, av.w, wp4[(dq * 4 + 3) * 32 + kg]);
    }
    ((float4*)S)[1024 + rg * 32 + kg] = acc;   // q at float 4096
  }
  __syncthreads();

  // ---- u[r][dd] = sum_k q[r][k] WphiT[k][dd]; thread = (cg=tid&127, rh) ----
  {
    const int cg = tid & 127;
    const int rh = tid >> 7;                   // rows rh*4 .. rh*4+3
    float4 acc[4];
#pragma unroll
    for (int i = 0; i < 4; ++i) acc[i] = make_float4(0.f, 0.f, 0.f, 0.f);
    const float4* wt4 = (const float4*)WphiT;
    const float4* q4  = (const float4*)S + 1024;
#pragma unroll 2
    for (int kq = 0; kq < 32; ++kq) {
      float4 q0 = q4[(rh * 4 + 0) * 32 + kq];  // uniform LDS broadcast
      float4 q1 = q4[(rh * 4 + 1) * 32 + kq];
      float4 q2 = q4[(rh * 4 + 2) * 32 + kq];
      float4 q3 = q4[(rh * 4 + 3) * 32 + kq];
      float qa[4] = {q0.x, q0.y, q0.z, q0.w};
      float qb[4] = {q1.x, q1.y, q1.z, q1.w};
      float qc[4] = {q2.x, q2.y, q2.z, q2.w};
      float qd[4] = {q3.x, q3.y, q3.z, q3.w};
#pragma unroll
      for (int j = 0; j < 4; ++j) {
        float4 wt = wt4[(kq * 4 + j) * 128 + cg];   // 1KB/wave coalesced
        fma4(acc[0], qa[j], wt);
        fma4(acc[1], qb[j], wt);
        fma4(acc[2], qc[j], wt);
        fma4(acc[3], qd[j], wt);
      }
    }
    float4* u4 = (float4*)S + 1280;              // u at float 5120
#pragma unroll
    for (int i = 0; i < 4; ++i) u4[(rh * 4 + i) * 128 + cg] = acc[i];
  }
  __syncthreads();

  // ---- u -> registers: wave w keeps its 2 rows, lane slice d in [8l,8l+8) ----
  const float4* u4r = (const float4*)S + 1280;
  const float4 u00 = u4r[(2 * w)     * 128 + 2 * lane];
  const float4 u01 = u4r[(2 * w)     * 128 + 2 * lane + 1];
  const float4 u10 = u4r[(2 * w + 1) * 128 + 2 * lane];
  const float4 u11 = u4r[(2 * w + 1) * 128 + 2 * lane + 1];
  __syncthreads();   // everyone's u reads done before any DMA overwrites scratch

  // ---- async V pipeline: chunk a = [8 rows][a][512]; wave-private 4KB piece ----
#define PF(A_) { \
    const float* s0p = V + (((size_t)((g0 + 2 * w) * 16 + (A_))) << 9) + (lane << 2); \
    const float* s1p = s0p + 8192; /* row 2w+1, same a */ \
    AS3 float* dp = (AS3 float*)(S + ((A_) & 3) * 4096 + w * 1024); \
    __builtin_amdgcn_global_load_lds((const AS1 void*)s0p,         (AS3 void*)(dp),       16, 0, 0); \
    __builtin_amdgcn_global_load_lds((const AS1 void*)(s0p + 256), (AS3 void*)(dp + 256), 16, 0, 0); \
    __builtin_amdgcn_global_load_lds((const AS1 void*)s1p,         (AS3 void*)(dp + 512), 16, 0, 0); \
    __builtin_amdgcn_global_load_lds((const AS1 void*)(s1p + 256), (AS3 void*)(dp + 768), 16, 0, 0); \
  }

  float a0[16], a1[16];

#define DOTC(A_) { \
    const float4* vb = (const float4*)(S + ((A_) & 3) * 4096 + w * 1024) + 2 * lane; \
    float4 p0 = vb[0], p1 = vb[1], r0 = vb[128], r1 = vb[129]; \
    float s0 = p0.x * u00.x; \
    s0 = fmaf(p0.y, u00.y, s0); s0 = fmaf(p0.z, u00.z, s0); s0 = fmaf(p0.w, u00.w, s0); \
    s0 = fmaf(p1.x, u01.x, s0); s0 = fmaf(p1.y, u01.y, s0); \
    s0 = fmaf(p1.z, u01.z, s0); s0 = fmaf(p1.w, u01.w, s0); \
    float s1 = r0.x * u10.x; \
    s1 = fmaf(r0.y, u10.y, s1); s1 = fmaf(r0.z, u10.z, s1); s1 = fmaf(r0.w, u10.w, s1); \
    s1 = fmaf(r1.x, u11.x, s1); s1 = fmaf(r1.y, u11.y, s1); \
    s1 = fmaf(r1.z, u11.z, s1); s1 = fmaf(r1.w, u11.w, s1); \
    a0[A_] = s0; a1[A_] = s1; \
  }

  // prologue: 3 chunks in flight (12 loads/wave)
  PF(0); PF(1); PF(2);

  // steady state: wait counted vmcnt(8) = 2 younger chunks outstanding
  WAITVM(8); DOTC(0);  PF(3);
  WAITVM(8); DOTC(1);  PF(4);
  WAITVM(8); DOTC(2);  PF(5);
  WAITVM(8); DOTC(3);  PF(6);
  WAITVM(8); DOTC(4);  PF(7);
  WAITVM(8); DOTC(5);  PF(8);
  WAITVM(8); DOTC(6);  PF(9);
  WAITVM(8); DOTC(7);  PF(10);
  WAITVM(8); DOTC(8);  PF(11);
  WAITVM(8); DOTC(9);  PF(12);
  WAITVM(8); DOTC(10); PF(13);
  WAITVM(8); DOTC(11); PF(14);
  WAITVM(8); DOTC(12); PF(15);
  WAITVM(8); DOTC(13);
  WAITVM(4); DOTC(14);
  WAITVM(0); DOTC(15);

  // ---- cross-lane reduce (deferred), then softmax per row ----
#pragma unroll
  for (int a = 0; a < 16; ++a) { a0[a] = wave_sum(a0[a]); a1[a] = wave_sum(a1[a]); }

  {
    float mx = a0[0];
#pragma unroll
    for (int a = 1; a < 16; ++a) mx = fmaxf(mx, a0[a]);
    float ss = 0.f;
#pragma unroll
    for (int a = 0; a < 16; ++a) { a0[a] = __expf(a0[a] - mx); ss += a0[a]; }
    float inv = 1.0f / ss;
#pragma unroll
    for (int a = 0; a < 16; ++a) a0[a] *= inv;
  }
  {
    float mx = a1[0];
#pragma unroll
    for (int a = 1; a < 16; ++a) mx = fmaxf(mx, a1[a]);
    float ss = 0.f;
#pragma unroll
    for (int a = 0; a < 16; ++a) { a1[a] = __expf(a1[a] - mx); ss += a1[a]; }
    float inv = 1.0f / ss;
#pragma unroll
    for (int a = 0; a < 16; ++a) a1[a] *= inv;
  }

  if (lane == 0) {
    float4* o0 = (float4*)(Out + (size_t)(g0 + 2 * w) * 16);
    o0[0] = make_float4(a0[0],  a0[1],  a0[2],  a0[3]);
    o0[1] = make_float4(a0[4],  a0[5],  a0[6],  a0[7]);
    o0[2] = make_float4(a0[8],  a0[9],  a0[10], a0[11]);
    o0[3] = make_float4(a0[12], a0[13], a0[14], a0[15]);
    float4* o1 = (float4*)(Out + (size_t)(g0 + 2 * w + 1) * 16);
    o1[0] = make_float4(a1[0],  a1[1],  a1[2],  a1[3]);
    o1[1] = make_float4(a1[4],  a1[5],  a1[6],  a1[7]);
    o1[2] = make_float4(a1[8],  a1[9],  a1[10], a1[11]);
    o1[3] = make_float4(a1[12], a1[13], a1[14], a1[15]);
  }
}

extern "C" void kernel_launch(void* const* d_in, const int* in_sizes, int n_in,
                              void* d_out, int out_size, void* d_ws, size_t ws_size,
                              hipStream_t stream) {
  (void)in_sizes; (void)n_in; (void)out_size; (void)ws_size;
  const float* A    = (const float*)d_in[0];  // agent_observation (128,32,512)
  const float* V    = (const float*)d_in[1];  // visible_observations (128,32,16,512)
  const float* Wpsi = (const float*)d_in[2];  // (512,128)
  const float* Wphi = (const float*)d_in[3];  // (512,128)
  float* Out   = (float*)d_out;               // (4096,16) fp32
  float* WphiT = (float*)d_ws;                // 256 KB

  transpose_wphi_k<<<256, 256, 0, stream>>>(Wphi, WphiT);
  entity_attn_k<<<512, 256, 0, stream>>>(A, V, Wpsi, WphiT, Out);
}

// Round 5
// 61.695 us; speedup vs baseline: 1.3664x; 1.1426x over previous
//
#include <hip/hip_runtime.h>
#include <math.h>

#define AS1 __attribute__((address_space(1)))
#define AS3 __attribute__((address_space(3)))

// K0: WphiT[k][dd] = Wphi[dd][k]  (128x512 fp32, 256 KB)
__global__ void transpose_wphi_k(const float* __restrict__ wphi,
                                 float* __restrict__ wphiT) {
  int idx = blockIdx.x * 256 + threadIdx.x;   // 0..65535
  int k  = idx >> 9;
  int dd = idx & 511;
  wphiT[idx] = wphi[dd * 128 + k];
}

__device__ __forceinline__ void fma4(float4& a, float s, const float4& w) {
  a.x = fmaf(s, w.x, a.x);
  a.y = fmaf(s, w.y, a.y);
  a.z = fmaf(s, w.z, a.z);
  a.w = fmaf(s, w.w, a.w);
}

__device__ __forceinline__ float wave_sum(float v) {
  v += __shfl_xor(v, 32, 64);
  v += __shfl_xor(v, 16, 64);
  v += __shfl_xor(v,  8, 64);
  v += __shfl_xor(v,  4, 64);
  v += __shfl_xor(v,  2, 64);
  v += __shfl_xor(v,  1, 64);
  return v;
}

// Persistent: 256 blocks (1/CU) x 512 threads (8 waves), 16 rows/block.
// Weights cross L2 exactly ONCE per CU, staged via async global_load_lds
// into a 2x32KB LDS ring; staging of tile t+1 hides under compute of t.
// LDS floats:
//   Astage [0, 8192)       16 x 512                (32 KB)
//   Wring  [8192, 24576)   2 x 8192 (tiles)        (64 KB)
//   qS     [24576, 26624)  16 x 128                ( 8 KB)
//   uS     [26624, 34816)  16 x 512                (32 KB)
__launch_bounds__(512, 2)
__global__ void entity_attn_k(const float* __restrict__ A,     // (4096,512)
                              const float* __restrict__ V,     // (4096,16,512)
                              const float* __restrict__ Wpsi,  // (512,128)
                              const float* __restrict__ WphiT, // (128,512) ws
                              float* __restrict__ Out)         // (4096,16)
{
  __shared__ __align__(16) float S[34816];   // 136 KB
  const int tid  = threadIdx.x;
  const int lane = tid & 63;
  const int w    = tid >> 6;                 // wave 0..7
  const int g0   = blockIdx.x * 16;

  // Stage one 8192-float (32KB) weight tile into ring slot R.
  // Per wave: 4 x global_load_lds width 16 (wave-uniform dst + lane*16B).
#define PFW(SRC, R, T) { \
    const float* sp = (SRC) + (T) * 8192 + w * 1024 + lane * 4; \
    AS3 float* dp = (AS3 float*)(S + 8192 + (R) * 8192 + w * 1024); \
    __builtin_amdgcn_global_load_lds((const AS1 void*)(sp),       (AS3 void*)(dp),       16, 0, 0); \
    __builtin_amdgcn_global_load_lds((const AS1 void*)(sp + 256), (AS3 void*)(dp + 256), 16, 0, 0); \
    __builtin_amdgcn_global_load_lds((const AS1 void*)(sp + 512), (AS3 void*)(dp + 512), 16, 0, 0); \
    __builtin_amdgcn_global_load_lds((const AS1 void*)(sp + 768), (AS3 void*)(dp + 768), 16, 0, 0); \
  }

  // ---- stage A (16 rows, coalesced f4) + prefetch Wpsi tile 0 ----
  {
    const float4* src = (const float4*)(A + (size_t)g0 * 512);
    float4* dst = (float4*)S;
#pragma unroll
    for (int j = 0; j < 4; ++j) dst[tid + j * 512] = src[tid + j * 512];
  }
  PFW(Wpsi, 0, 0);
  __syncthreads();   // compiler drains vmcnt+lgkmcnt before s_barrier

  // ---- phase 1: q[r][k] = sum_d A[r][d] Wpsi[d][k] ----
  // thread = (kq = tid&31 -> k f4-group, r = tid>>5 -> row 0..15)
  // 8 tiles of 64 d-rows; compute tile t from ring[t&1] while t+1 stages.
  {
    const int kq = tid & 31;
    const int r  = tid >> 5;
    float4 qacc = make_float4(0.f, 0.f, 0.f, 0.f);
    for (int t = 0; t < 8; ++t) {
      if (t < 7) PFW(Wpsi, (t + 1) & 1, t + 1);
      const float4* wt = (const float4*)(S + 8192 + (t & 1) * 8192);
      const float* ar  = S + r * 512 + t * 64;
#pragma unroll
      for (int i = 0; i < 64; ++i) {
        float  a  = ar[i];            // uniform-per-half-wave LDS broadcast
        float4 w4 = wt[i * 32 + kq];  // conflict-free f4
        fma4(qacc, a, w4);
      }
      __syncthreads();                // tile t+1 arrived; ring swap safe
    }
    ((float4*)(S + 24576))[r * 32 + kq] = qacc;
  }
  PFW(WphiT, 0, 0);
  __syncthreads();

  // ---- phase 2: u[r][dd] = sum_k q[r][k] WphiT[k][dd] ----
  // thread = (ddq = tid&127 -> dd f4-group, rg = tid>>7 -> rows rg*4..+3)
  // 8 tiles of 16 k-rows.
  {
    const int ddq = tid & 127;
    const int rg  = tid >> 7;
    float4 uacc[4];
#pragma unroll
    for (int i = 0; i < 4; ++i) uacc[i] = make_float4(0.f, 0.f, 0.f, 0.f);
    const float* qrow = S + 24576;
    for (int t = 0; t < 8; ++t) {
      if (t < 7) PFW(WphiT, (t + 1) & 1, t + 1);
      const float4* wt = (const float4*)(S + 8192 + (t & 1) * 8192);
#pragma unroll
      for (int i = 0; i < 16; ++i) {
        const int k = t * 16 + i;
        float4 w4 = wt[i * 128 + ddq];          // conflict-free f4
        float q0 = qrow[(rg * 4 + 0) * 128 + k]; // wave-uniform broadcasts
        float q1 = qrow[(rg * 4 + 1) * 128 + k];
        float q2 = qrow[(rg * 4 + 2) * 128 + k];
        float q3 = qrow[(rg * 4 + 3) * 128 + k];
        fma4(uacc[0], q0, w4);
        fma4(uacc[1], q1, w4);
        fma4(uacc[2], q2, w4);
        fma4(uacc[3], q3, w4);
      }
      __syncthreads();
    }
    float4* u4 = (float4*)(S + 26624);
#pragma unroll
    for (int i = 0; i < 4; ++i) u4[(rg * 4 + i) * 128 + ddq] = uacc[i];
  }
  __syncthreads();

  // ---- phase 3: wave w streams rows 2w, 2w+1 (direct loads, 32-deep MLP) ----
  const float4* u4r = (const float4*)(S + 26624);
  const float4 u00 = u4r[(2 * w)     * 128 + 2 * lane];
  const float4 u01 = u4r[(2 * w)     * 128 + 2 * lane + 1];
  const float4 u10 = u4r[(2 * w + 1) * 128 + 2 * lane];
  const float4 u11 = u4r[(2 * w + 1) * 128 + 2 * lane + 1];

  float a0[16], a1[16];
  {
    const float4* v0 = (const float4*)V + (size_t)(g0 + 2 * w) * 2048;
    const float4* v1 = (const float4*)V + (size_t)(g0 + 2 * w + 1) * 2048;
#pragma unroll
    for (int ag = 0; ag < 2; ++ag) {
      float4 va[16];
#pragma unroll
      for (int j = 0; j < 8; ++j) {
        va[j * 2]     = v0[(size_t)(ag * 8 + j) * 128 + 2 * lane];
        va[j * 2 + 1] = v0[(size_t)(ag * 8 + j) * 128 + 2 * lane + 1];
      }
#pragma unroll
      for (int j = 0; j < 8; ++j) {
        float s;
        s = va[j*2].x * u00.x;
        s = fmaf(va[j*2].y, u00.y, s);
        s = fmaf(va[j*2].z, u00.z, s);
        s = fmaf(va[j*2].w, u00.w, s);
        s = fmaf(va[j*2+1].x, u01.x, s);
        s = fmaf(va[j*2+1].y, u01.y, s);
        s = fmaf(va[j*2+1].z, u01.z, s);
        s = fmaf(va[j*2+1].w, u01.w, s);
        a0[ag * 8 + j] = s;
      }
    }
#pragma unroll
    for (int ag = 0; ag < 2; ++ag) {
      float4 va[16];
#pragma unroll
      for (int j = 0; j < 8; ++j) {
        va[j * 2]     = v1[(size_t)(ag * 8 + j) * 128 + 2 * lane];
        va[j * 2 + 1] = v1[(size_t)(ag * 8 + j) * 128 + 2 * lane + 1];
      }
#pragma unroll
      for (int j = 0; j < 8; ++j) {
        float s;
        s = va[j*2].x * u10.x;
        s = fmaf(va[j*2].y, u10.y, s);
        s = fmaf(va[j*2].z, u10.z, s);
        s = fmaf(va[j*2].w, u10.w, s);
        s = fmaf(va[j*2+1].x, u11.x, s);
        s = fmaf(va[j*2+1].y, u11.y, s);
        s = fmaf(va[j*2+1].z, u11.z, s);
        s = fmaf(va[j*2+1].w, u11.w, s);
        a1[ag * 8 + j] = s;
      }
    }
  }

#pragma unroll
  for (int a = 0; a < 16; ++a) { a0[a] = wave_sum(a0[a]); a1[a] = wave_sum(a1[a]); }

  {
    float mx = a0[0];
#pragma unroll
    for (int a = 1; a < 16; ++a) mx = fmaxf(mx, a0[a]);
    float ss = 0.f;
#pragma unroll
    for (int a = 0; a < 16; ++a) { a0[a] = __expf(a0[a] - mx); ss += a0[a]; }
    float inv = 1.0f / ss;
#pragma unroll
    for (int a = 0; a < 16; ++a) a0[a] *= inv;
  }
  {
    float mx = a1[0];
#pragma unroll
    for (int a = 1; a < 16; ++a) mx = fmaxf(mx, a1[a]);
    float ss = 0.f;
#pragma unroll
    for (int a = 0; a < 16; ++a) { a1[a] = __expf(a1[a] - mx); ss += a1[a]; }
    float inv = 1.0f / ss;
#pragma unroll
    for (int a = 0; a < 16; ++a) a1[a] *= inv;
  }

  if (lane == 0) {
    float4* o0 = (float4*)(Out + (size_t)(g0 + 2 * w) * 16);
    o0[0] = make_float4(a0[0],  a0[1],  a0[2],  a0[3]);
    o0[1] = make_float4(a0[4],  a0[5],  a0[6],  a0[7]);
    o0[2] = make_float4(a0[8],  a0[9],  a0[10], a0[11]);
    o0[3] = make_float4(a0[12], a0[13], a0[14], a0[15]);
    float4* o1 = (float4*)(Out + (size_t)(g0 + 2 * w + 1) * 16);
    o1[0] = make_float4(a1[0],  a1[1],  a1[2],  a1[3]);
    o1[1] = make_float4(a1[4],  a1[5],  a1[6],  a1[7]);
    o1[2] = make_float4(a1[8],  a1[9],  a1[10], a1[11]);
    o1[3] = make_float4(a1[12], a1[13], a1[14], a1[15]);
  }
}

extern "C" void kernel_launch(void* const* d_in, const int* in_sizes, int n_in,
                              void* d_out, int out_size, void* d_ws, size_t ws_size,
                              hipStream_t stream) {
  (void)in_sizes; (void)n_in; (void)out_size; (void)ws_size;
  const float* A    = (const float*)d_in[0];  // agent_observation (128,32,512)
  const float* V    = (const float*)d_in[1];  // visible_observations (128,32,16,512)
  const float* Wpsi = (const float*)d_in[2];  // (512,128)
  const float* Wphi = (const float*)d_in[3];  // (512,128)
  float* Out   = (float*)d_out;               // (4096,16) fp32
  float* WphiT = (float*)d_ws;                // 256 KB

  transpose_wphi_k<<<256, 256, 0, stream>>>(Wphi, WphiT);
  entity_attn_k<<<256, 512, 0, stream>>>(A, V, Wpsi, WphiT, Out);
}